// Round 17
// baseline (14387.267 us; speedup 1.0000x reference)
//
#include <hip/hip_runtime.h>
#include <math.h>

#define D 512
#define THRESH 0.5f
#define NMAX 8192
#define TOPK 64
#define INFI 0x7fffffff

typedef short bhalf8 __attribute__((ext_vector_type(8)));
typedef float f32x4 __attribute__((ext_vector_type(4)));

__global__ void k_init(int* dn, int n) { *dn = n; }

// fused: norms + fp32->bf16 (RNE) + partner=-1 init. One block (128 thr)/row.
__global__ void k_prep(const float* __restrict__ E, float* __restrict__ norms,
                       unsigned short* __restrict__ H, int* __restrict__ partner,
                       const int* __restrict__ dn) {
    int n = *dn;
    int row = blockIdx.x;
    if (row >= n) return;
    int t = threadIdx.x; // 0..127
    float4 v = ((const float4*)(E + (size_t)row * D))[t];
    float s = v.x * v.x + v.y * v.y + v.z * v.z + v.w * v.w;
    #pragma unroll
    for (int o = 32; o > 0; o >>= 1) s += __shfl_down(s, o, 64);
    __shared__ float ls[2];
    if ((t & 63) == 0) ls[t >> 6] = s;
    float f[4] = {v.x, v.y, v.z, v.w};
    unsigned short r[4];
    #pragma unroll
    for (int u = 0; u < 4; ++u) {
        unsigned int b = __float_as_uint(f[u]);
        r[u] = (unsigned short)((b + 0x7FFFu + ((b >> 16) & 1u)) >> 16);
    }
    uint2 packed;
    packed.x = (unsigned)r[0] | ((unsigned)r[1] << 16);
    packed.y = (unsigned)r[2] | ((unsigned)r[3] << 16);
    *(uint2*)(H + (size_t)row * D + t * 4) = packed;
    if (t == 64) partner[row] = -1;
    __syncthreads();
    if (t == 0) norms[row] = fmaxf(sqrtf(ls[0] + ls[1]), 1e-8f);
}

// sim tile via bf16 MFMA: 128x128 block tile, 4 waves (2x2), BK=64, K=512.
#define LDSTRIDE 72
__global__ void __launch_bounds__(256) k_mfma_sim(
    const unsigned short* __restrict__ H, const float* __restrict__ norms,
    float* __restrict__ sim, int tile_start, int TR, int simStride,
    const int* __restrict__ dn)
{
    int n = *dn;
    if (tile_start >= n) return;
    int row0 = tile_start + blockIdx.y * 128;
    int col0 = blockIdx.x * 128;
    if (row0 >= n || col0 >= n) return;
    if (col0 + 128 <= row0 + 1) return;     // triangle skip

    __shared__ unsigned short As[128 * LDSTRIDE];
    __shared__ unsigned short Bs[128 * LDSTRIDE];
    int tid = threadIdx.x;
    int lane = tid & 63;
    int wave = tid >> 6;
    int wr = wave >> 1;
    int wc = wave & 1;
    int krow = lane & 15;
    int kgrp = (lane >> 4) * 8;

    f32x4 acc[4][4];
    #pragma unroll
    for (int m = 0; m < 4; ++m)
        #pragma unroll
        for (int t = 0; t < 4; ++t)
            acc[m][t] = (f32x4){0.f, 0.f, 0.f, 0.f};

    for (int k0 = 0; k0 < D; k0 += 64) {
        #pragma unroll
        for (int it = 0; it < 4; ++it) {
            int c  = tid + it * 256;
            int rr = c >> 3;
            int cc = c & 7;
            uint4 va = make_uint4(0, 0, 0, 0);
            int gra = row0 + rr;
            if (gra < n) va = *(const uint4*)(H + (size_t)gra * D + k0 + cc * 8);
            *(uint4*)&As[rr * LDSTRIDE + cc * 8] = va;
            uint4 vb = make_uint4(0, 0, 0, 0);
            int grb = col0 + rr;
            if (grb < n) vb = *(const uint4*)(H + (size_t)grb * D + k0 + cc * 8);
            *(uint4*)&Bs[rr * LDSTRIDE + cc * 8] = vb;
        }
        __syncthreads();
        #pragma unroll
        for (int kk = 0; kk < 64; kk += 32) {
            bhalf8 a[4], b[4];
            #pragma unroll
            for (int m = 0; m < 4; ++m)
                a[m] = *(const bhalf8*)&As[(wr * 64 + m * 16 + krow) * LDSTRIDE + kk + kgrp];
            #pragma unroll
            for (int t = 0; t < 4; ++t)
                b[t] = *(const bhalf8*)&Bs[(wc * 64 + t * 16 + krow) * LDSTRIDE + kk + kgrp];
            #pragma unroll
            for (int m = 0; m < 4; ++m)
                #pragma unroll
                for (int t = 0; t < 4; ++t)
                    acc[m][t] = __builtin_amdgcn_mfma_f32_16x16x32_bf16(a[m], b[t], acc[m][t], 0, 0, 0);
        }
        __syncthreads();
    }

    int fcol = lane & 15;
    int frow = (lane >> 4) * 4;
    #pragma unroll
    for (int m = 0; m < 4; ++m) {
        #pragma unroll
        for (int t = 0; t < 4; ++t) {
            #pragma unroll
            for (int v = 0; v < 4; ++v) {
                int gr = row0 + wr * 64 + m * 16 + frow + v;
                int gc = col0 + wc * 64 + t * 16 + fcol;
                if (gr < n && gc < n)
                    sim[(size_t)(gr - tile_start) * simStride + gc] =
                        acc[m][t][v] / (norms[gr] * norms[gc]);
            }
        }
    }
}

// per-row exact top-64 (val desc, idx asc) among j>i. One wave per row.
__global__ void __launch_bounds__(64) k_topk(
    const float* __restrict__ sim, int tile_start, int TR, int simStride,
    uint2* __restrict__ tkP, int* __restrict__ needFix,
    const int* __restrict__ dn)
{
    int n = *dn;
    int r = blockIdx.x;
    int i = tile_start + r;
    if (r >= TR || i >= n) return;
    int lane = threadIdx.x;
    const float* srow = sim + (size_t)r * simStride;

    float v[8]; int id[8];
    #pragma unroll
    for (int u = 0; u < 8; ++u) { v[u] = -INFINITY; id[u] = INFI; }
    float ovV = -INFINITY; int ovI = INFI;

    for (int j = i + 1 + lane; j < n; j += 64) {
        float x = srow[j];
        if (x > v[7] || (x == v[7] && j < id[7])) {
            if (v[7] > ovV || (v[7] == ovV && id[7] < ovI)) { ovV = v[7]; ovI = id[7]; }
            int p = 7;
            #pragma unroll
            for (int u = 6; u >= 0; --u) {
                bool mv = (x > v[u]) || (x == v[u] && j < id[u]);
                if (mv) { v[u + 1] = v[u]; id[u + 1] = id[u]; p = u; }
            }
            v[p] = x; id[p] = j;
        } else {
            if (x > ovV || (x == ovV && j < ovI)) { ovV = x; ovI = j; }
        }
    }

    int pos = 0;
    float myV = -INFINITY; int myI = INFI;
    for (int k = 0; k < TOPK; ++k) {
        float hv = (pos < 8) ? v[pos] : -INFINITY;
        int   hi = (pos < 8) ? id[pos] : INFI;
        float bv = hv; int bi = hi;
        #pragma unroll
        for (int o = 1; o < 64; o <<= 1) {
            float xv = __shfl_xor(bv, o, 64);
            int   xi = __shfl_xor(bi, o, 64);
            if (xv > bv || (xv == bv && xi < bi)) { bv = xv; bi = xi; }
        }
        if (pos < 8 && hv == bv && hi == bi) pos++;
        if (k == lane) { myV = bv; myI = bi; }
    }
    tkP[(size_t)i * TOPK + lane] = make_uint2(__float_as_uint(myV), (unsigned)myI);

    float v64 = __shfl(myV, 63, 64);
    int   i64 = __shfl(myI, 63, 64);
    float oV = ovV; int oI = ovI;
    #pragma unroll
    for (int o = 1; o < 64; o <<= 1) {
        float xv = __shfl_xor(oV, o, 64);
        int   xi = __shfl_xor(oI, o, 64);
        if (xv > oV || (xv == oV && xi < oI)) { oV = xv; oI = xi; }
    }
    int bad = (oV > v64) || (oV == v64 && oI < i64);
    if (lane == 0) needFix[i] = bad;
}

// rare exact redo: per-lane top-64 lists in LDS (unconditionally exact)
__global__ void __launch_bounds__(64) k_topkfix(
    const float* __restrict__ sim, int tile_start, int TR, int simStride,
    uint2* __restrict__ tkP, const int* __restrict__ needFix,
    const int* __restrict__ dn)
{
    int n = *dn;
    int r = blockIdx.x;
    int i = tile_start + r;
    if (r >= TR || i >= n) return;
    if (!needFix[i]) return;
    int lane = threadIdx.x;
    __shared__ float lv[64][TOPK];
    __shared__ int   li[64][TOPK];
    for (int u = 0; u < TOPK; ++u) { lv[lane][u] = -INFINITY; li[lane][u] = INFI; }
    const float* srow = sim + (size_t)r * simStride;
    for (int j = i + 1 + lane; j < n; j += 64) {
        float x = srow[j];
        float wv = lv[lane][TOPK - 1]; int wi = li[lane][TOPK - 1];
        if (x > wv || (x == wv && j < wi)) {
            int p = TOPK - 1;
            for (int u = TOPK - 2; u >= 0; --u) {
                float uv = lv[lane][u]; int ui = li[lane][u];
                if (x > uv || (x == uv && j < ui)) { lv[lane][u + 1] = uv; li[lane][u + 1] = ui; p = u; }
                else break;
            }
            lv[lane][p] = x; li[lane][p] = j;
        }
    }
    int pos = 0;
    float myV = -INFINITY; int myI = INFI;
    for (int k = 0; k < TOPK; ++k) {
        float hv = (pos < TOPK) ? lv[lane][pos] : -INFINITY;
        int   hi = (pos < TOPK) ? li[lane][pos] : INFI;
        float bv = hv; int bi = hi;
        #pragma unroll
        for (int o = 1; o < 64; o <<= 1) {
            float xv = __shfl_xor(bv, o, 64);
            int   xi = __shfl_xor(bi, o, 64);
            if (xv > bv || (xv == bv && xi < bi)) { bv = xv; bi = xi; }
        }
        if (pos < TOPK && hv == bv && hi == bi) pos++;
        if (k == lane) { myV = bv; myI = bi; }
    }
    tkP[(size_t)i * TOPK + lane] = make_uint2(__float_as_uint(myV), (unsigned)myI);
}

// fallback: masked lex-argmax over precomputed sim row (sim resident)
__device__ __attribute__((noinline)) void sim_fallback(
    int r, int n, int lane, const float* __restrict__ sim, int simStride,
    const volatile unsigned long long* lmask, float& obv, int& obj)
{
    const float* srow = sim + (size_t)r * simStride;
    float bv = -INFINITY; int bj = INFI;
    for (int jb = (r + 1) & ~63; jb < n; jb += 64) {
        int j2 = jb + lane;
        unsigned long long wm = lmask[j2 >> 6];
        bool ok2 = (j2 > r) && (j2 < n) && !((wm >> (j2 & 63)) & 1ull);
        float v2 = ok2 ? srow[j2] : -INFINITY;
        int   i2 = ok2 ? j2 : INFI;
        if (v2 > bv || (v2 == bv && i2 < bj)) { bv = v2; bj = i2; }
    }
    #pragma unroll
    for (int o = 1; o < 64; o <<= 1) {
        float xv = __shfl_xor(bv, o, 64);
        int   xi = __shfl_xor(bj, o, 64);
        if (xv > bv || (xv == bv && xi < bj)) { bv = xv; bj = xi; }
    }
    obv = bv; obj = bj;
}

// dot-product fallback (only if sim matrix not fully resident)
__device__ __attribute__((noinline)) void dot_fallback(
    int r, int n, int lane, const float* __restrict__ E,
    const float* __restrict__ norms, const volatile unsigned long long* lmask,
    float& obv, int& obj)
{
    float ni = norms[r];
    float4 e0 = *(const float4*)(E + (size_t)r * D + lane * 8);
    float4 e1 = *(const float4*)(E + (size_t)r * D + lane * 8 + 4);
    float bbv = -INFINITY; int bbj = INFI;
    int w0 = (r + 1) >> 6, wN = (n + 63) >> 6;
    for (int ww = w0; ww < wN; ++ww) {
        unsigned long long um = ~lmask[ww];
        if (ww == (r >> 6)) um &= (~0ull) << ((r & 63) + 1);
        int over = (ww << 6) + 64 - n;
        if (over > 0) um &= (over >= 64) ? 0ull : ((~0ull) >> over);
        while (um) {
            int b = __builtin_ctzll(um);
            um &= um - 1;
            int jj = (ww << 6) + b;
            float4 a0 = *(const float4*)(E + (size_t)jj * D + lane * 8);
            float4 a1 = *(const float4*)(E + (size_t)jj * D + lane * 8 + 4);
            float s = e0.x * a0.x + e0.y * a0.y + e0.z * a0.z + e0.w * a0.w
                    + e1.x * a1.x + e1.y * a1.y + e1.z * a1.z + e1.w * a1.w;
            #pragma unroll
            for (int o = 1; o < 64; o <<= 1) s += __shfl_xor(s, o, 64);
            float sv = s / (ni * norms[jj]);
            if (sv > bbv || (sv == bbv && jj < bbj)) { bbv = sv; bbj = jj; }
        }
    }
    obv = bbv; obj = bbj;
}

// greedy scan, one wave (block 0, wave 0), lane-per-row windows of 64 with
// claim-table resolution — round-12 design (best known). All OTHER waves of
// all blocks run an n-proportional FMA burner so the DPM governor keeps
// clocks boosted while the serial chain runs. Burner is deterministic,
// shorter than the scan it shadows, and has no semantic effect.
__global__ void __launch_bounds__(256) k_scan11(
    const uint2* __restrict__ tkP,
    const float* __restrict__ E, const float* __restrict__ norms,
    const float* __restrict__ sim, int simStride, int simOk,
    int* __restrict__ partner, int* __restrict__ srcIdx,
    int* __restrict__ dn)
{
    if (blockIdx.x != 0 || threadIdx.x >= 64) {
        // ---- clock-keeper burner ----
        int nb = *dn;
        float x = (float)(threadIdx.x + blockIdx.x * 7 + 1);
        int iters = nb * 24;
        for (int it = 0; it < iters; ++it)
            x = fmaf(x, 0.99999988f, 1.0e-7f);
        asm volatile("" :: "v"(x));   // keep live, no DCE
        return;
    }

    int n = *dn;
    int lane = threadIdx.x;
    int base_ = lane << 7;

    __shared__ unsigned int lmask32[NMAX / 32];   // merged bits
    __shared__ unsigned int cmask32[NMAX / 32];   // consumed-as-j bits
    __shared__ unsigned int claim[NMAX];          // stamped claim table
    __shared__ int wslot[64];
    for (int i = lane; i < NMAX / 32; i += 64) { lmask32[i] = 0u; cmask32[i] = 0u; }
    for (int i = lane; i < NMAX; i += 64) claim[i] = 0xFFFFFFFFu;
    asm volatile("s_waitcnt lgkmcnt(0)" ::: "memory");

    unsigned wcounter = 0x3FFFFFFu;   // decreasing -> newer stamps smaller
    const unsigned long long* lm64 = (const unsigned long long*)lmask32;

#define WINDOW(U0, U1, LO) {                                                   \
    long long kw_ = (long long)(LO) - base_;                                   \
    if (kw_ > 0) {                                                             \
        if (kw_ >= 128) { U0 = 0ull; U1 = 0ull; }                              \
        else if (kw_ >= 64) { U0 = 0ull; if (kw_ > 64) U1 &= (~0ull) << (int)(kw_ - 64); } \
        else U0 &= (~0ull) << (int)kw_;                                        \
    }                                                                          \
    int kn_ = n - base_;                                                       \
    if (kn_ <= 0) { U0 = 0ull; U1 = 0ull; }                                    \
    else if (kn_ < 64) { U0 &= (~0ull) >> (64 - kn_); U1 = 0ull; }             \
    else if (kn_ < 128) { U1 = (kn_ == 64) ? 0ull : (U1 & ((~0ull) >> (128 - kn_))); } }

    int cursor = 0;
    int guardW = NMAX / 32 + 32;
    while (cursor < n && guardW-- > 0) {
        // ---- window selection: next 64 unmerged rows >= cursor ----
        unsigned a0 = lmask32[4 * lane + 0], a1 = lmask32[4 * lane + 1];
        unsigned a2 = lmask32[4 * lane + 2], a3 = lmask32[4 * lane + 3];
        unsigned long long u0 = ~(((unsigned long long)a1 << 32) | a0);
        unsigned long long u1 = ~(((unsigned long long)a3 << 32) | a2);
        WINDOW(u0, u1, cursor)
        int myCnt = __builtin_popcountll(u0) + __builtin_popcountll(u1);
        int incl = myCnt;
        #pragma unroll
        for (int o = 1; o < 64; o <<= 1) {
            int t = __shfl_up(incl, o, 64);
            if (lane >= o) incl += t;
        }
        int excl = incl - myCnt;
        int total = __builtin_amdgcn_readlane(incl, 63);
        if (total == 0) break;
        if (excl < 64 && myCnt) {
            int rk = excl;
            unsigned long long t0 = u0;
            while (t0 && rk < 64) { int b = __builtin_ctzll(t0); t0 &= t0 - 1; wslot[rk] = base_ + b; ++rk; }
            unsigned long long t1 = u1;
            while (t1 && rk < 64) { int b = __builtin_ctzll(t1); t1 &= t1 - 1; wslot[rk] = base_ + 64 + b; ++rk; }
        }
        asm volatile("s_waitcnt lgkmcnt(0)" ::: "memory");
        int nw = (total < 64) ? total : 64;
        int selR = (lane < nw) ? wslot[lane] : INFI;
        cursor = (total > 64) ? (__builtin_amdgcn_readlane(selR, 63) + 1) : n;

        // ---- candidate gather (top-8 per lane, 64B) ----
        uint2 c0, c1, c2, c3, c4, c5, c6, c7;
        {
            unsigned sent = 0xFF800000u;
            c0 = c1 = c2 = c3 = c4 = c5 = c6 = c7 = make_uint2(sent, (unsigned)INFI);
            if (selR != INFI) {
                const uint4* p = (const uint4*)(tkP + (size_t)selR * TOPK);
                uint4 g0 = p[0]; uint4 g1 = p[1]; uint4 g2 = p[2]; uint4 g3 = p[3];
                c0 = make_uint2(g0.x, g0.y); c1 = make_uint2(g0.z, g0.w);
                c2 = make_uint2(g1.x, g1.y); c3 = make_uint2(g1.z, g1.w);
                c4 = make_uint2(g2.x, g2.y); c5 = make_uint2(g2.z, g2.w);
                c6 = make_uint2(g3.x, g3.y); c7 = make_uint2(g3.z, g3.w);
            }
        }

        wcounter--;                           // fresh stamp for this window
        unsigned stampCur = wcounter << 6;
        bool resolved = (selR == INFI);

        int guardI = 700;
        while (guardI-- > 0) {
            unsigned long long unres = __ballot(!resolved);
            if (!unres) break;

            // ---- bulk revalidate (independent LDS reads) ----
            bool rowMerged = false;
            int vld = 0;
            if (!resolved) {
                unsigned wrw = lmask32[selR >> 5];
                rowMerged = (wrw >> (selR & 31)) & 1u;
            }
            if (!resolved && !rowMerged) {
#define CHK(ck, bit) { int ci_ = (int)ck.y; if (ci_ < n) {                      \
                unsigned wm_ = lmask32[ci_ >> 5];                               \
                if (!((wm_ >> (ci_ & 31)) & 1u)) vld |= bit; } }
                CHK(c0, 1) CHK(c1, 2) CHK(c2, 4) CHK(c3, 8)
                CHK(c4, 16) CHK(c5, 32) CHK(c6, 64) CHK(c7, 128)
#undef CHK
            }
            if (!resolved && rowMerged) resolved = true;   // consumed earlier

            // ---- pick + threshold resolve ----
            int pj = INFI; float pvf = -INFINITY;
            bool exhausted = false;
            if (!resolved) {
                if (vld) {
                    int t_ = __builtin_ctz((unsigned)vld);
                    int jx, vx;
                    if (t_ == 0)      { jx = (int)c0.y; vx = (int)c0.x; }
                    else if (t_ == 1) { jx = (int)c1.y; vx = (int)c1.x; }
                    else if (t_ == 2) { jx = (int)c2.y; vx = (int)c2.x; }
                    else if (t_ == 3) { jx = (int)c3.y; vx = (int)c3.x; }
                    else if (t_ == 4) { jx = (int)c4.y; vx = (int)c4.x; }
                    else if (t_ == 5) { jx = (int)c5.y; vx = (int)c5.x; }
                    else if (t_ == 6) { jx = (int)c6.y; vx = (int)c6.x; }
                    else              { jx = (int)c7.y; vx = (int)c7.x; }
                    pj = jx; pvf = __uint_as_float((unsigned)vx);
                    if (pvf < THRESH) resolved = true;   // partner stays -1
                } else exhausted = true;
            }

            // ---- parallel claims ----
            bool claiming = (!resolved && vld != 0);
            unsigned stampLane = stampCur | (unsigned)lane;
            if (claiming) atomicMin(&claim[pj], stampLane);
            asm volatile("s_waitcnt lgkmcnt(0)" ::: "memory");

            bool won = false, rowStamped = false;
            int rcLane = 64;
            if (claiming) won = (claim[pj] == stampLane);
            if (!resolved) {
                unsigned rc = claim[selR];
                rowStamped = ((rc >> 6) == wcounter);
                rcLane = (int)(rc & 63u);
            }

            // ---- hard trouble & bulk commit ----
            bool hard = !resolved && (exhausted || (claiming && !won));
            unsigned long long hb = __ballot(hard);
            int T = hb ? (int)__builtin_ctzll(hb) : 64;
            bool commit = claiming && won && !rowStamped && (lane < T);
            if (commit) {
                atomicOr(&lmask32[selR >> 5], 1u << (selR & 31));
                atomicOr(&lmask32[pj >> 5], 1u << (pj & 31));
                atomicOr(&cmask32[pj >> 5], 1u << (pj & 31));
                partner[selR] = pj;
                resolved = true;
            }
            unsigned long long cb = __ballot(commit);
            // bulk consume: my row claimed by a lane that committed this iter
            if (!resolved && rowStamped && rcLane < 64 && ((cb >> rcLane) & 1ull)) {
                if (claiming && won) claim[pj] = 0xFFFFFFFFu;  // void my claim
                resolved = true;
            }
            asm volatile("s_waitcnt lgkmcnt(0)" ::: "memory");

            // ---- serial slow path: first unresolved lane is exhausted ----
            unsigned long long su = __ballot(!resolved);
            if (su) {
                int Fu = (int)__builtin_ctzll(su);
                int fex = __builtin_amdgcn_readlane((int)(exhausted ? 1 : 0), Fu);
                if (fex) {
                    int r_ = __builtin_amdgcn_readlane(selR, Fu);
                    // coalesced rescan of full 64-candidate list
                    uint2 q = tkP[(size_t)r_ * TOPK + lane];
                    int ci = (int)q.y;
                    unsigned wm = lmask32[(ci < n) ? (ci >> 5) : 0];
                    bool val2 = (ci < n) && !((wm >> (ci & 31)) & 1u);
                    unsigned long long bal2 = __ballot(val2);
                    int j_ = -1; float v_ = -INFINITY;
                    if (bal2) {
                        int L2 = (int)__builtin_ctzll(bal2);
                        j_ = __builtin_amdgcn_readlane(ci, L2);
                        v_ = __uint_as_float((unsigned)__builtin_amdgcn_readlane((int)q.x, L2));
                    } else {
                        unsigned b0 = lmask32[4 * lane + 0], b1 = lmask32[4 * lane + 1];
                        unsigned b2 = lmask32[4 * lane + 2], b3 = lmask32[4 * lane + 3];
                        unsigned long long s0 = ~(((unsigned long long)b1 << 32) | b0);
                        unsigned long long s1 = ~(((unsigned long long)b3 << 32) | b2);
                        WINDOW(s0, s1, r_ + 1)
                        if (__ballot((s0 | s1) != 0ull)) {
                            if (simOk) sim_fallback(r_, n, lane, sim, simStride,
                                                    (const volatile unsigned long long*)lm64, v_, j_);
                            else       dot_fallback(r_, n, lane, E, norms,
                                                    (const volatile unsigned long long*)lm64, v_, j_);
                            if (j_ == INFI) j_ = -1;
                        }
                    }
                    if (j_ >= 0 && v_ >= THRESH) {
                        if (lane == 0) {
                            atomicOr(&lmask32[r_ >> 5], 1u << (r_ & 31));
                            atomicOr(&lmask32[j_ >> 5], 1u << (j_ & 31));
                            atomicOr(&cmask32[j_ >> 5], 1u << (j_ & 31));
                            partner[r_] = j_;
                        }
                    }
                    if (lane == Fu) resolved = true;
                    asm volatile("s_waitcnt lgkmcnt(0)" ::: "memory");
                }
            }
        }
    }

    // fused survivor compaction: survivors = rows not consumed-as-j
    {
        asm volatile("s_waitcnt lgkmcnt(0)" ::: "memory");
        unsigned d0 = cmask32[4 * lane + 0], d1 = cmask32[4 * lane + 1];
        unsigned d2 = cmask32[4 * lane + 2], d3 = cmask32[4 * lane + 3];
        unsigned long long s0 = ~(((unsigned long long)d1 << 32) | d0);
        unsigned long long s1 = ~(((unsigned long long)d3 << 32) | d2);
        int base = lane << 7;
        int kn = n - base;
        if (kn <= 0) { s0 = 0ull; s1 = 0ull; }
        else if (kn < 64) { s0 &= (~0ull) >> (64 - kn); s1 = 0ull; }
        else if (kn < 128) { s1 = (kn == 64) ? 0ull : (s1 & ((~0ull) >> (128 - kn))); }
        int cnt = __builtin_popcountll(s0) + __builtin_popcountll(s1);
        int inc = cnt;
        #pragma unroll
        for (int o = 1; o < 64; o <<= 1) {
            int t = __shfl_up(inc, o, 64);
            if (lane >= o) inc += t;
        }
        int p = inc - cnt;
        while (s0) { int b = __builtin_ctzll(s0); s0 &= s0 - 1; srcIdx[p++] = base + b; }
        while (s1) { int b = __builtin_ctzll(s1); s1 &= s1 - 1; srcIdx[p++] = base + 64 + b; }
        if (lane == 63) *dn = inc;
    }
#undef WINDOW
}

// fused[i] = partner>=0 ? min(e_i + e_p, 1) : e_i ; compact into nxt
__global__ void k_fuse(const float* __restrict__ cur, float* __restrict__ nxt,
                       const int* __restrict__ srcIdx, const int* __restrict__ partner,
                       const int* __restrict__ dn) {
    int nn = *dn;
    int k = blockIdx.x;
    if (k >= nn) return;
    int t = threadIdx.x;     // 0..127
    int i = srcIdx[k];
    int p = partner[i];
    float4 v = ((const float4*)(cur + (size_t)i * D))[t];
    if (p >= 0) {
        float4 w = ((const float4*)(cur + (size_t)p * D))[t];
        v.x = fminf(v.x + w.x, 1.0f);
        v.y = fminf(v.y + w.y, 1.0f);
        v.z = fminf(v.z + w.z, 1.0f);
        v.w = fminf(v.w + w.w, 1.0f);
    }
    ((float4*)(nxt + (size_t)k * D))[t] = v;
}

__global__ void k_copyout(const float* __restrict__ src, float* __restrict__ dst, int nelem) {
    int i = blockIdx.x * 256 + threadIdx.x;
    if (i < nelem) dst[i] = src[i];
}

extern "C" void kernel_launch(void* const* d_in, const int* in_sizes, int n_in,
                              void* d_out, int out_size, void* d_ws, size_t ws_size,
                              hipStream_t stream) {
    const float* input = (const float*)d_in[0];
    const int N0 = in_sizes[0] / D;   // 8192
    char* ws = (char*)d_ws;

    const size_t embA = (size_t)(N0 / 2) * D * sizeof(float);    // 8 MB
    const size_t embB = (size_t)(N0 / 4) * D * sizeof(float);    // 4 MB
    const size_t embH = (size_t)N0 * D * sizeof(unsigned short); // 8 MB
    float* bufA = (float*)ws;
    float* bufB = (float*)(ws + embA);
    unsigned short* curh = (unsigned short*)(ws + embA + embB);
    char* aux = ws + embA + embB + embH;
    float* norms   = (float*)(aux);
    int*   partner = (int*)(aux + 32 * 1024);
    int*   srcIdx  = (int*)(aux + 96 * 1024);
    int*   dn      = (int*)(aux + 128 * 1024);
    int*   needFix = (int*)(aux + 160 * 1024);
    uint2* tkP     = (uint2*)(aux + 256 * 1024);
    float* simTile = (float*)(aux + 256 * 1024 + (size_t)NMAX * TOPK * 8);
    const size_t fixedBytes = embA + embB + embH + 256 * 1024 + (size_t)NMAX * TOPK * 8;

    int TR = NMAX;
    while (TR > 128 && fixedBytes + (size_t)TR * N0 * sizeof(float) > ws_size) TR >>= 1;
    int simOk = (TR == N0) ? 1 : 0;

    const int ROUNDS = 16;
    k_init<<<1, 1, 0, stream>>>(dn, N0);
    for (int r = 0; r < ROUNDS; ++r) {
        const float* cur = (r == 0) ? input : ((r & 1) ? bufA : bufB);
        float* nxt = (r & 1) ? bufB : bufA;
        k_prep<<<N0, 128, 0, stream>>>(cur, norms, curh, partner, dn);
        int NT = N0 / TR;
        for (int t = 0; t < NT; ++t) {
            dim3 g(N0 / 128, TR / 128);
            k_mfma_sim<<<g, 256, 0, stream>>>(curh, norms, simTile, t * TR, TR, N0, dn);
            k_topk<<<TR, 64, 0, stream>>>(simTile, t * TR, TR, N0, tkP, needFix, dn);
            k_topkfix<<<TR, 64, 0, stream>>>(simTile, t * TR, TR, N0, tkP, needFix, dn);
        }
        k_scan11<<<256, 256, 0, stream>>>(tkP, cur, norms, simTile, N0, simOk, partner, srcIdx, dn);
        k_fuse<<<N0, 128, 0, stream>>>(cur, nxt, srcIdx, partner, dn);
    }
    float* fin = bufB;   // ROUNDS-1 = 15 is odd -> last write went to bufB
    k_copyout<<<(out_size + 255) / 256, 256, 0, stream>>>(fin, (float*)d_out, out_size);
}

// Round 18
// 13760.429 us; speedup vs baseline: 1.0456x; 1.0456x over previous
//
#include <hip/hip_runtime.h>
#include <math.h>

#define D 512
#define THRESH 0.5f
#define NMAX 8192
#define TOPK 64
#define INFI 0x7fffffff

typedef short bhalf8 __attribute__((ext_vector_type(8)));
typedef float f32x4 __attribute__((ext_vector_type(4)));

__global__ void k_init(int* dn, int n) { *dn = n; }

// fused: norms + fp32->bf16 (RNE) + partner=-1 init. One block (128 thr)/row.
__global__ void k_prep(const float* __restrict__ E, float* __restrict__ norms,
                       unsigned short* __restrict__ H, int* __restrict__ partner,
                       const int* __restrict__ dn) {
    int n = *dn;
    int row = blockIdx.x;
    if (row >= n) return;
    int t = threadIdx.x; // 0..127
    float4 v = ((const float4*)(E + (size_t)row * D))[t];
    float s = v.x * v.x + v.y * v.y + v.z * v.z + v.w * v.w;
    #pragma unroll
    for (int o = 32; o > 0; o >>= 1) s += __shfl_down(s, o, 64);
    __shared__ float ls[2];
    if ((t & 63) == 0) ls[t >> 6] = s;
    float f[4] = {v.x, v.y, v.z, v.w};
    unsigned short r[4];
    #pragma unroll
    for (int u = 0; u < 4; ++u) {
        unsigned int b = __float_as_uint(f[u]);
        r[u] = (unsigned short)((b + 0x7FFFu + ((b >> 16) & 1u)) >> 16);
    }
    uint2 packed;
    packed.x = (unsigned)r[0] | ((unsigned)r[1] << 16);
    packed.y = (unsigned)r[2] | ((unsigned)r[3] << 16);
    *(uint2*)(H + (size_t)row * D + t * 4) = packed;
    if (t == 64) partner[row] = -1;
    __syncthreads();
    if (t == 0) norms[row] = fmaxf(sqrtf(ls[0] + ls[1]), 1e-8f);
}

// sim tile via bf16 MFMA: 128x128 block tile, 4 waves (2x2), BK=64, K=512.
#define LDSTRIDE 72
__global__ void __launch_bounds__(256) k_mfma_sim(
    const unsigned short* __restrict__ H, const float* __restrict__ norms,
    float* __restrict__ sim, int tile_start, int TR, int simStride,
    const int* __restrict__ dn)
{
    int n = *dn;
    if (tile_start >= n) return;
    int row0 = tile_start + blockIdx.y * 128;
    int col0 = blockIdx.x * 128;
    if (row0 >= n || col0 >= n) return;
    if (col0 + 128 <= row0 + 1) return;     // triangle skip

    __shared__ unsigned short As[128 * LDSTRIDE];
    __shared__ unsigned short Bs[128 * LDSTRIDE];
    int tid = threadIdx.x;
    int lane = tid & 63;
    int wave = tid >> 6;
    int wr = wave >> 1;
    int wc = wave & 1;
    int krow = lane & 15;
    int kgrp = (lane >> 4) * 8;

    f32x4 acc[4][4];
    #pragma unroll
    for (int m = 0; m < 4; ++m)
        #pragma unroll
        for (int t = 0; t < 4; ++t)
            acc[m][t] = (f32x4){0.f, 0.f, 0.f, 0.f};

    for (int k0 = 0; k0 < D; k0 += 64) {
        #pragma unroll
        for (int it = 0; it < 4; ++it) {
            int c  = tid + it * 256;
            int rr = c >> 3;
            int cc = c & 7;
            uint4 va = make_uint4(0, 0, 0, 0);
            int gra = row0 + rr;
            if (gra < n) va = *(const uint4*)(H + (size_t)gra * D + k0 + cc * 8);
            *(uint4*)&As[rr * LDSTRIDE + cc * 8] = va;
            uint4 vb = make_uint4(0, 0, 0, 0);
            int grb = col0 + rr;
            if (grb < n) vb = *(const uint4*)(H + (size_t)grb * D + k0 + cc * 8);
            *(uint4*)&Bs[rr * LDSTRIDE + cc * 8] = vb;
        }
        __syncthreads();
        #pragma unroll
        for (int kk = 0; kk < 64; kk += 32) {
            bhalf8 a[4], b[4];
            #pragma unroll
            for (int m = 0; m < 4; ++m)
                a[m] = *(const bhalf8*)&As[(wr * 64 + m * 16 + krow) * LDSTRIDE + kk + kgrp];
            #pragma unroll
            for (int t = 0; t < 4; ++t)
                b[t] = *(const bhalf8*)&Bs[(wc * 64 + t * 16 + krow) * LDSTRIDE + kk + kgrp];
            #pragma unroll
            for (int m = 0; m < 4; ++m)
                #pragma unroll
                for (int t = 0; t < 4; ++t)
                    acc[m][t] = __builtin_amdgcn_mfma_f32_16x16x32_bf16(a[m], b[t], acc[m][t], 0, 0, 0);
        }
        __syncthreads();
    }

    int fcol = lane & 15;
    int frow = (lane >> 4) * 4;
    #pragma unroll
    for (int m = 0; m < 4; ++m) {
        #pragma unroll
        for (int t = 0; t < 4; ++t) {
            #pragma unroll
            for (int v = 0; v < 4; ++v) {
                int gr = row0 + wr * 64 + m * 16 + frow + v;
                int gc = col0 + wc * 64 + t * 16 + fcol;
                if (gr < n && gc < n)
                    sim[(size_t)(gr - tile_start) * simStride + gc] =
                        acc[m][t][v] / (norms[gr] * norms[gc]);
            }
        }
    }
}

// per-row exact top-64 (val desc, idx asc) among j>i. One wave per row.
__global__ void __launch_bounds__(64) k_topk(
    const float* __restrict__ sim, int tile_start, int TR, int simStride,
    uint2* __restrict__ tkP, int* __restrict__ needFix,
    const int* __restrict__ dn)
{
    int n = *dn;
    int r = blockIdx.x;
    int i = tile_start + r;
    if (r >= TR || i >= n) return;
    int lane = threadIdx.x;
    const float* srow = sim + (size_t)r * simStride;

    float v[8]; int id[8];
    #pragma unroll
    for (int u = 0; u < 8; ++u) { v[u] = -INFINITY; id[u] = INFI; }
    float ovV = -INFINITY; int ovI = INFI;

    for (int j = i + 1 + lane; j < n; j += 64) {
        float x = srow[j];
        if (x > v[7] || (x == v[7] && j < id[7])) {
            if (v[7] > ovV || (v[7] == ovV && id[7] < ovI)) { ovV = v[7]; ovI = id[7]; }
            int p = 7;
            #pragma unroll
            for (int u = 6; u >= 0; --u) {
                bool mv = (x > v[u]) || (x == v[u] && j < id[u]);
                if (mv) { v[u + 1] = v[u]; id[u + 1] = id[u]; p = u; }
            }
            v[p] = x; id[p] = j;
        } else {
            if (x > ovV || (x == ovV && j < ovI)) { ovV = x; ovI = j; }
        }
    }

    int pos = 0;
    float myV = -INFINITY; int myI = INFI;
    for (int k = 0; k < TOPK; ++k) {
        float hv = (pos < 8) ? v[pos] : -INFINITY;
        int   hi = (pos < 8) ? id[pos] : INFI;
        float bv = hv; int bi = hi;
        #pragma unroll
        for (int o = 1; o < 64; o <<= 1) {
            float xv = __shfl_xor(bv, o, 64);
            int   xi = __shfl_xor(bi, o, 64);
            if (xv > bv || (xv == bv && xi < bi)) { bv = xv; bi = xi; }
        }
        if (pos < 8 && hv == bv && hi == bi) pos++;
        if (k == lane) { myV = bv; myI = bi; }
    }
    tkP[(size_t)i * TOPK + lane] = make_uint2(__float_as_uint(myV), (unsigned)myI);

    float v64 = __shfl(myV, 63, 64);
    int   i64 = __shfl(myI, 63, 64);
    float oV = ovV; int oI = ovI;
    #pragma unroll
    for (int o = 1; o < 64; o <<= 1) {
        float xv = __shfl_xor(oV, o, 64);
        int   xi = __shfl_xor(oI, o, 64);
        if (xv > oV || (xv == oV && xi < oI)) { oV = xv; oI = xi; }
    }
    int bad = (oV > v64) || (oV == v64 && oI < i64);
    if (lane == 0) needFix[i] = bad;
}

// rare exact redo: per-lane top-64 lists in LDS (unconditionally exact)
__global__ void __launch_bounds__(64) k_topkfix(
    const float* __restrict__ sim, int tile_start, int TR, int simStride,
    uint2* __restrict__ tkP, const int* __restrict__ needFix,
    const int* __restrict__ dn)
{
    int n = *dn;
    int r = blockIdx.x;
    int i = tile_start + r;
    if (r >= TR || i >= n) return;
    if (!needFix[i]) return;
    int lane = threadIdx.x;
    __shared__ float lv[64][TOPK];
    __shared__ int   li[64][TOPK];
    for (int u = 0; u < TOPK; ++u) { lv[lane][u] = -INFINITY; li[lane][u] = INFI; }
    const float* srow = sim + (size_t)r * simStride;
    for (int j = i + 1 + lane; j < n; j += 64) {
        float x = srow[j];
        float wv = lv[lane][TOPK - 1]; int wi = li[lane][TOPK - 1];
        if (x > wv || (x == wv && j < wi)) {
            int p = TOPK - 1;
            for (int u = TOPK - 2; u >= 0; --u) {
                float uv = lv[lane][u]; int ui = li[lane][u];
                if (x > uv || (x == uv && j < ui)) { lv[lane][u + 1] = uv; li[lane][u + 1] = ui; p = u; }
                else break;
            }
            lv[lane][p] = x; li[lane][p] = j;
        }
    }
    int pos = 0;
    float myV = -INFINITY; int myI = INFI;
    for (int k = 0; k < TOPK; ++k) {
        float hv = (pos < TOPK) ? lv[lane][pos] : -INFINITY;
        int   hi = (pos < TOPK) ? li[lane][pos] : INFI;
        float bv = hv; int bi = hi;
        #pragma unroll
        for (int o = 1; o < 64; o <<= 1) {
            float xv = __shfl_xor(bv, o, 64);
            int   xi = __shfl_xor(bi, o, 64);
            if (xv > bv || (xv == bv && xi < bi)) { bv = xv; bi = xi; }
        }
        if (pos < TOPK && hv == bv && hi == bi) pos++;
        if (k == lane) { myV = bv; myI = bi; }
    }
    tkP[(size_t)i * TOPK + lane] = make_uint2(__float_as_uint(myV), (unsigned)myI);
}

// fallback: masked lex-argmax over precomputed sim row (sim resident).
// 8-block batches: all 8 LDS mask reads + 8 coalesced sim reads issued
// BEFORE any use (static register arrays) -> ~8 outstanding loads per
// batch instead of one dependent load pair per 64 columns.
__device__ __attribute__((noinline)) void sim_fallback(
    int r, int n, int lane, const float* __restrict__ sim, int simStride,
    const unsigned long long* lmask, float& obv, int& obj)
{
    const float* srow = sim + (size_t)r * simStride;
    float bv = -INFINITY; int bj = INFI;
    int jb0 = (r + 1) & ~63;
    for (int jb = jb0; jb < n; jb += 512) {
        float vv[8]; unsigned long long wm[8];
        #pragma unroll
        for (int u = 0; u < 8; ++u) {
            int j2 = jb + u * 64 + lane;
            bool inr = (j2 < n);
            wm[u] = inr ? lmask[j2 >> 6] : ~0ull;
            vv[u] = inr ? srow[j2] : -INFINITY;
        }
        #pragma unroll
        for (int u = 0; u < 8; ++u) {
            int j2 = jb + u * 64 + lane;
            bool ok2 = (j2 > r) && (j2 < n) && !((wm[u] >> (j2 & 63)) & 1ull);
            float v2 = ok2 ? vv[u] : -INFINITY;
            int   i2 = ok2 ? j2 : INFI;
            if (v2 > bv || (v2 == bv && i2 < bj)) { bv = v2; bj = i2; }
        }
    }
    #pragma unroll
    for (int o = 1; o < 64; o <<= 1) {
        float xv = __shfl_xor(bv, o, 64);
        int   xi = __shfl_xor(bj, o, 64);
        if (xv > bv || (xv == bv && xi < bj)) { bv = xv; bj = xi; }
    }
    obv = bv; obj = bj;
}

// dot-product fallback (only if sim matrix not fully resident)
__device__ __attribute__((noinline)) void dot_fallback(
    int r, int n, int lane, const float* __restrict__ E,
    const float* __restrict__ norms, const unsigned long long* lmask,
    float& obv, int& obj)
{
    float ni = norms[r];
    float4 e0 = *(const float4*)(E + (size_t)r * D + lane * 8);
    float4 e1 = *(const float4*)(E + (size_t)r * D + lane * 8 + 4);
    float bbv = -INFINITY; int bbj = INFI;
    int w0 = (r + 1) >> 6, wN = (n + 63) >> 6;
    for (int ww = w0; ww < wN; ++ww) {
        unsigned long long um = ~lmask[ww];
        if (ww == (r >> 6)) um &= (~0ull) << ((r & 63) + 1);
        int over = (ww << 6) + 64 - n;
        if (over > 0) um &= (over >= 64) ? 0ull : ((~0ull) >> over);
        while (um) {
            int b = __builtin_ctzll(um);
            um &= um - 1;
            int jj = (ww << 6) + b;
            float4 a0 = *(const float4*)(E + (size_t)jj * D + lane * 8);
            float4 a1 = *(const float4*)(E + (size_t)jj * D + lane * 8 + 4);
            float s = e0.x * a0.x + e0.y * a0.y + e0.z * a0.z + e0.w * a0.w
                    + e1.x * a1.x + e1.y * a1.y + e1.z * a1.z + e1.w * a1.w;
            #pragma unroll
            for (int o = 1; o < 64; o <<= 1) s += __shfl_xor(s, o, 64);
            float sv = s / (ni * norms[jj]);
            if (sv > bbv || (sv == bbv && jj < bbj)) { bbv = sv; bbj = jj; }
        }
    }
    obv = bbv; obj = bbj;
}

// greedy scan, one wave, lane-per-row windows of 64 with claim-table
// resolution (round-12 design, best known).
__global__ void __launch_bounds__(64) k_scan11(
    const uint2* __restrict__ tkP,
    const float* __restrict__ E, const float* __restrict__ norms,
    const float* __restrict__ sim, int simStride, int simOk,
    int* __restrict__ partner, int* __restrict__ srcIdx,
    int* __restrict__ dn)
{
    int n = *dn;
    int lane = threadIdx.x;
    int base_ = lane << 7;

    __shared__ unsigned int lmask32[NMAX / 32];   // merged bits
    __shared__ unsigned int cmask32[NMAX / 32];   // consumed-as-j bits
    __shared__ unsigned int claim[NMAX];          // stamped claim table
    __shared__ int wslot[64];
    for (int i = lane; i < NMAX / 32; i += 64) { lmask32[i] = 0u; cmask32[i] = 0u; }
    for (int i = lane; i < NMAX; i += 64) claim[i] = 0xFFFFFFFFu;
    asm volatile("s_waitcnt lgkmcnt(0)" ::: "memory");

    unsigned wcounter = 0x3FFFFFFu;   // decreasing -> newer stamps smaller
    const unsigned long long* lm64 = (const unsigned long long*)lmask32;

#define WINDOW(U0, U1, LO) {                                                   \
    long long kw_ = (long long)(LO) - base_;                                   \
    if (kw_ > 0) {                                                             \
        if (kw_ >= 128) { U0 = 0ull; U1 = 0ull; }                              \
        else if (kw_ >= 64) { U0 = 0ull; if (kw_ > 64) U1 &= (~0ull) << (int)(kw_ - 64); } \
        else U0 &= (~0ull) << (int)kw_;                                        \
    }                                                                          \
    int kn_ = n - base_;                                                       \
    if (kn_ <= 0) { U0 = 0ull; U1 = 0ull; }                                    \
    else if (kn_ < 64) { U0 &= (~0ull) >> (64 - kn_); U1 = 0ull; }             \
    else if (kn_ < 128) { U1 = (kn_ == 64) ? 0ull : (U1 & ((~0ull) >> (128 - kn_))); } }

    int cursor = 0;
    int guardW = NMAX / 32 + 32;
    while (cursor < n && guardW-- > 0) {
        // ---- window selection: next 64 unmerged rows >= cursor ----
        unsigned a0 = lmask32[4 * lane + 0], a1 = lmask32[4 * lane + 1];
        unsigned a2 = lmask32[4 * lane + 2], a3 = lmask32[4 * lane + 3];
        unsigned long long u0 = ~(((unsigned long long)a1 << 32) | a0);
        unsigned long long u1 = ~(((unsigned long long)a3 << 32) | a2);
        WINDOW(u0, u1, cursor)
        int myCnt = __builtin_popcountll(u0) + __builtin_popcountll(u1);
        int incl = myCnt;
        #pragma unroll
        for (int o = 1; o < 64; o <<= 1) {
            int t = __shfl_up(incl, o, 64);
            if (lane >= o) incl += t;
        }
        int excl = incl - myCnt;
        int total = __builtin_amdgcn_readlane(incl, 63);
        if (total == 0) break;
        if (excl < 64 && myCnt) {
            int rk = excl;
            unsigned long long t0 = u0;
            while (t0 && rk < 64) { int b = __builtin_ctzll(t0); t0 &= t0 - 1; wslot[rk] = base_ + b; ++rk; }
            unsigned long long t1 = u1;
            while (t1 && rk < 64) { int b = __builtin_ctzll(t1); t1 &= t1 - 1; wslot[rk] = base_ + 64 + b; ++rk; }
        }
        asm volatile("s_waitcnt lgkmcnt(0)" ::: "memory");
        int nw = (total < 64) ? total : 64;
        int selR = (lane < nw) ? wslot[lane] : INFI;
        cursor = (total > 64) ? (__builtin_amdgcn_readlane(selR, 63) + 1) : n;

        // ---- candidate gather (top-8 per lane, 64B) ----
        uint2 c0, c1, c2, c3, c4, c5, c6, c7;
        {
            unsigned sent = 0xFF800000u;
            c0 = c1 = c2 = c3 = c4 = c5 = c6 = c7 = make_uint2(sent, (unsigned)INFI);
            if (selR != INFI) {
                const uint4* p = (const uint4*)(tkP + (size_t)selR * TOPK);
                uint4 g0 = p[0]; uint4 g1 = p[1]; uint4 g2 = p[2]; uint4 g3 = p[3];
                c0 = make_uint2(g0.x, g0.y); c1 = make_uint2(g0.z, g0.w);
                c2 = make_uint2(g1.x, g1.y); c3 = make_uint2(g1.z, g1.w);
                c4 = make_uint2(g2.x, g2.y); c5 = make_uint2(g2.z, g2.w);
                c6 = make_uint2(g3.x, g3.y); c7 = make_uint2(g3.z, g3.w);
            }
        }

        wcounter--;                           // fresh stamp for this window
        unsigned stampCur = wcounter << 6;
        bool resolved = (selR == INFI);

        int guardI = 700;
        while (guardI-- > 0) {
            unsigned long long unres = __ballot(!resolved);
            if (!unres) break;

            // ---- bulk revalidate (independent LDS reads) ----
            bool rowMerged = false;
            int vld = 0;
            if (!resolved) {
                unsigned wrw = lmask32[selR >> 5];
                rowMerged = (wrw >> (selR & 31)) & 1u;
            }
            if (!resolved && !rowMerged) {
#define CHK(ck, bit) { int ci_ = (int)ck.y; if (ci_ < n) {                      \
                unsigned wm_ = lmask32[ci_ >> 5];                               \
                if (!((wm_ >> (ci_ & 31)) & 1u)) vld |= bit; } }
                CHK(c0, 1) CHK(c1, 2) CHK(c2, 4) CHK(c3, 8)
                CHK(c4, 16) CHK(c5, 32) CHK(c6, 64) CHK(c7, 128)
#undef CHK
            }
            if (!resolved && rowMerged) resolved = true;   // consumed earlier

            // ---- pick + threshold resolve ----
            int pj = INFI; float pvf = -INFINITY;
            bool exhausted = false;
            if (!resolved) {
                if (vld) {
                    int t_ = __builtin_ctz((unsigned)vld);
                    int jx, vx;
                    if (t_ == 0)      { jx = (int)c0.y; vx = (int)c0.x; }
                    else if (t_ == 1) { jx = (int)c1.y; vx = (int)c1.x; }
                    else if (t_ == 2) { jx = (int)c2.y; vx = (int)c2.x; }
                    else if (t_ == 3) { jx = (int)c3.y; vx = (int)c3.x; }
                    else if (t_ == 4) { jx = (int)c4.y; vx = (int)c4.x; }
                    else if (t_ == 5) { jx = (int)c5.y; vx = (int)c5.x; }
                    else if (t_ == 6) { jx = (int)c6.y; vx = (int)c6.x; }
                    else              { jx = (int)c7.y; vx = (int)c7.x; }
                    pj = jx; pvf = __uint_as_float((unsigned)vx);
                    if (pvf < THRESH) resolved = true;   // partner stays -1
                } else exhausted = true;
            }

            // ---- parallel claims ----
            bool claiming = (!resolved && vld != 0);
            unsigned stampLane = stampCur | (unsigned)lane;
            if (claiming) atomicMin(&claim[pj], stampLane);
            asm volatile("s_waitcnt lgkmcnt(0)" ::: "memory");

            bool won = false, rowStamped = false;
            int rcLane = 64;
            if (claiming) won = (claim[pj] == stampLane);
            if (!resolved) {
                unsigned rc = claim[selR];
                rowStamped = ((rc >> 6) == wcounter);
                rcLane = (int)(rc & 63u);
            }

            // ---- hard trouble & bulk commit ----
            bool hard = !resolved && (exhausted || (claiming && !won));
            unsigned long long hb = __ballot(hard);
            int T = hb ? (int)__builtin_ctzll(hb) : 64;
            bool commit = claiming && won && !rowStamped && (lane < T);
            if (commit) {
                atomicOr(&lmask32[selR >> 5], 1u << (selR & 31));
                atomicOr(&lmask32[pj >> 5], 1u << (pj & 31));
                atomicOr(&cmask32[pj >> 5], 1u << (pj & 31));
                partner[selR] = pj;
                resolved = true;
            }
            unsigned long long cb = __ballot(commit);
            // bulk consume: my row claimed by a lane that committed this iter
            if (!resolved && rowStamped && rcLane < 64 && ((cb >> rcLane) & 1ull)) {
                if (claiming && won) claim[pj] = 0xFFFFFFFFu;  // void my claim
                resolved = true;
            }
            asm volatile("s_waitcnt lgkmcnt(0)" ::: "memory");

            // ---- serial slow path: first unresolved lane is exhausted ----
            unsigned long long su = __ballot(!resolved);
            if (su) {
                int Fu = (int)__builtin_ctzll(su);
                int fex = __builtin_amdgcn_readlane((int)(exhausted ? 1 : 0), Fu);
                if (fex) {
                    int r_ = __builtin_amdgcn_readlane(selR, Fu);
                    // coalesced rescan of full 64-candidate list
                    uint2 q = tkP[(size_t)r_ * TOPK + lane];
                    int ci = (int)q.y;
                    unsigned wm = lmask32[(ci < n) ? (ci >> 5) : 0];
                    bool val2 = (ci < n) && !((wm >> (ci & 31)) & 1u);
                    unsigned long long bal2 = __ballot(val2);
                    int j_ = -1; float v_ = -INFINITY;
                    if (bal2) {
                        int L2 = (int)__builtin_ctzll(bal2);
                        j_ = __builtin_amdgcn_readlane(ci, L2);
                        v_ = __uint_as_float((unsigned)__builtin_amdgcn_readlane((int)q.x, L2));
                    } else {
                        unsigned b0 = lmask32[4 * lane + 0], b1 = lmask32[4 * lane + 1];
                        unsigned b2 = lmask32[4 * lane + 2], b3 = lmask32[4 * lane + 3];
                        unsigned long long s0 = ~(((unsigned long long)b1 << 32) | b0);
                        unsigned long long s1 = ~(((unsigned long long)b3 << 32) | b2);
                        WINDOW(s0, s1, r_ + 1)
                        if (__ballot((s0 | s1) != 0ull)) {
                            if (simOk) sim_fallback(r_, n, lane, sim, simStride, lm64, v_, j_);
                            else       dot_fallback(r_, n, lane, E, norms, lm64, v_, j_);
                            if (j_ == INFI) j_ = -1;
                        }
                    }
                    if (j_ >= 0 && v_ >= THRESH) {
                        if (lane == 0) {
                            atomicOr(&lmask32[r_ >> 5], 1u << (r_ & 31));
                            atomicOr(&lmask32[j_ >> 5], 1u << (j_ & 31));
                            atomicOr(&cmask32[j_ >> 5], 1u << (j_ & 31));
                            partner[r_] = j_;
                        }
                    }
                    if (lane == Fu) resolved = true;
                    asm volatile("s_waitcnt lgkmcnt(0)" ::: "memory");
                }
            }
        }
    }

    // fused survivor compaction: survivors = rows not consumed-as-j
    {
        asm volatile("s_waitcnt lgkmcnt(0)" ::: "memory");
        unsigned d0 = cmask32[4 * lane + 0], d1 = cmask32[4 * lane + 1];
        unsigned d2 = cmask32[4 * lane + 2], d3 = cmask32[4 * lane + 3];
        unsigned long long s0 = ~(((unsigned long long)d1 << 32) | d0);
        unsigned long long s1 = ~(((unsigned long long)d3 << 32) | d2);
        int base = lane << 7;
        int kn = n - base;
        if (kn <= 0) { s0 = 0ull; s1 = 0ull; }
        else if (kn < 64) { s0 &= (~0ull) >> (64 - kn); s1 = 0ull; }
        else if (kn < 128) { s1 = (kn == 64) ? 0ull : (s1 & ((~0ull) >> (128 - kn))); }
        int cnt = __builtin_popcountll(s0) + __builtin_popcountll(s1);
        int inc = cnt;
        #pragma unroll
        for (int o = 1; o < 64; o <<= 1) {
            int t = __shfl_up(inc, o, 64);
            if (lane >= o) inc += t;
        }
        int p = inc - cnt;
        while (s0) { int b = __builtin_ctzll(s0); s0 &= s0 - 1; srcIdx[p++] = base + b; }
        while (s1) { int b = __builtin_ctzll(s1); s1 &= s1 - 1; srcIdx[p++] = base + 64 + b; }
        if (lane == 63) *dn = inc;
    }
#undef WINDOW
}

// fused[i] = partner>=0 ? min(e_i + e_p, 1) : e_i ; compact into nxt
__global__ void k_fuse(const float* __restrict__ cur, float* __restrict__ nxt,
                       const int* __restrict__ srcIdx, const int* __restrict__ partner,
                       const int* __restrict__ dn) {
    int nn = *dn;
    int k = blockIdx.x;
    if (k >= nn) return;
    int t = threadIdx.x;     // 0..127
    int i = srcIdx[k];
    int p = partner[i];
    float4 v = ((const float4*)(cur + (size_t)i * D))[t];
    if (p >= 0) {
        float4 w = ((const float4*)(cur + (size_t)p * D))[t];
        v.x = fminf(v.x + w.x, 1.0f);
        v.y = fminf(v.y + w.y, 1.0f);
        v.z = fminf(v.z + w.z, 1.0f);
        v.w = fminf(v.w + w.w, 1.0f);
    }
    ((float4*)(nxt + (size_t)k * D))[t] = v;
}

__global__ void k_copyout(const float* __restrict__ src, float* __restrict__ dst, int nelem) {
    int i = blockIdx.x * 256 + threadIdx.x;
    if (i < nelem) dst[i] = src[i];
}

extern "C" void kernel_launch(void* const* d_in, const int* in_sizes, int n_in,
                              void* d_out, int out_size, void* d_ws, size_t ws_size,
                              hipStream_t stream) {
    const float* input = (const float*)d_in[0];
    const int N0 = in_sizes[0] / D;   // 8192
    char* ws = (char*)d_ws;

    const size_t embA = (size_t)(N0 / 2) * D * sizeof(float);    // 8 MB
    const size_t embB = (size_t)(N0 / 4) * D * sizeof(float);    // 4 MB
    const size_t embH = (size_t)N0 * D * sizeof(unsigned short); // 8 MB
    float* bufA = (float*)ws;
    float* bufB = (float*)(ws + embA);
    unsigned short* curh = (unsigned short*)(ws + embA + embB);
    char* aux = ws + embA + embB + embH;
    float* norms   = (float*)(aux);
    int*   partner = (int*)(aux + 32 * 1024);
    int*   srcIdx  = (int*)(aux + 96 * 1024);
    int*   dn      = (int*)(aux + 128 * 1024);
    int*   needFix = (int*)(aux + 160 * 1024);
    uint2* tkP     = (uint2*)(aux + 256 * 1024);
    float* simTile = (float*)(aux + 256 * 1024 + (size_t)NMAX * TOPK * 8);
    const size_t fixedBytes = embA + embB + embH + 256 * 1024 + (size_t)NMAX * TOPK * 8;

    int TR = NMAX;
    while (TR > 128 && fixedBytes + (size_t)TR * N0 * sizeof(float) > ws_size) TR >>= 1;
    int simOk = (TR == N0) ? 1 : 0;

    const int ROUNDS = 16;
    k_init<<<1, 1, 0, stream>>>(dn, N0);
    for (int r = 0; r < ROUNDS; ++r) {
        const float* cur = (r == 0) ? input : ((r & 1) ? bufA : bufB);
        float* nxt = (r & 1) ? bufB : bufA;
        k_prep<<<N0, 128, 0, stream>>>(cur, norms, curh, partner, dn);
        int NT = N0 / TR;
        for (int t = 0; t < NT; ++t) {
            dim3 g(N0 / 128, TR / 128);
            k_mfma_sim<<<g, 256, 0, stream>>>(curh, norms, simTile, t * TR, TR, N0, dn);
            k_topk<<<TR, 64, 0, stream>>>(simTile, t * TR, TR, N0, tkP, needFix, dn);
            k_topkfix<<<TR, 64, 0, stream>>>(simTile, t * TR, TR, N0, tkP, needFix, dn);
        }
        k_scan11<<<1, 64, 0, stream>>>(tkP, cur, norms, simTile, N0, simOk, partner, srcIdx, dn);
        k_fuse<<<N0, 128, 0, stream>>>(cur, nxt, srcIdx, partner, dn);
    }
    float* fin = bufB;   // ROUNDS-1 = 15 is odd -> last write went to bufB
    k_copyout<<<(out_size + 255) / 256, 256, 0, stream>>>(fin, (float*)d_out, out_size);
}